// Round 1
// baseline (129.552 us; speedup 1.0000x reference)
//
#include <hip/hip_runtime.h>
#include <math.h>

#define B_SZ    1024
#define IN_DIM  512
#define OUT_DIM 512
#define EMB_DIM 64
#define KQ      64

#define BM 64
#define BN 32
#define BK 16

// ---------------------------------------------------------------------------
// Kernel A: coef[b, 0..2] = softmax(W2 @ tanh(W1 @ concat(emb_a, emb_c) + b1))
// One wave (64 lanes) per sample; lane j owns h[j].
// ---------------------------------------------------------------------------
__global__ __launch_bounds__(64) void coef_kernel(
    const int*   __restrict__ idx_a,
    const int*   __restrict__ idx_c,
    const float* __restrict__ emb_a,
    const float* __restrict__ emb_c,
    const float* __restrict__ W1,
    const float* __restrict__ b1,
    const float* __restrict__ W2,
    float4*      __restrict__ coef_out)
{
    const int s = blockIdx.x;
    const int j = threadIdx.x;  // 0..63

    const int ia = idx_a[s];
    const int ic = idx_c[s];

    const float4* ea  = (const float4*)(emb_a + (long)ia * EMB_DIM);
    const float4* ec  = (const float4*)(emb_c + (long)ic * EMB_DIM);
    const float4* w1a = (const float4*)(W1 + (long)j * (2 * EMB_DIM));
    const float4* w1c = (const float4*)(W1 + (long)j * (2 * EMB_DIM) + EMB_DIM);

    float acc = b1[j];
#pragma unroll
    for (int q = 0; q < EMB_DIM / 4; ++q) {
        float4 e = ea[q];
        float4 w = w1a[q];
        acc = fmaf(e.x, w.x, acc);
        acc = fmaf(e.y, w.y, acc);
        acc = fmaf(e.z, w.z, acc);
        acc = fmaf(e.w, w.w, acc);
    }
#pragma unroll
    for (int q = 0; q < EMB_DIM / 4; ++q) {
        float4 e = ec[q];
        float4 w = w1c[q];
        acc = fmaf(e.x, w.x, acc);
        acc = fmaf(e.y, w.y, acc);
        acc = fmaf(e.z, w.z, acc);
        acc = fmaf(e.w, w.w, acc);
    }

    float h = tanhf(acc);

    float p0 = W2[0 * KQ + j] * h;
    float p1 = W2[1 * KQ + j] * h;
    float p2 = W2[2 * KQ + j] * h;
#pragma unroll
    for (int off = 32; off > 0; off >>= 1) {
        p0 += __shfl_xor(p0, off);
        p1 += __shfl_xor(p1, off);
        p2 += __shfl_xor(p2, off);
    }

    // softmax over the 3 basis logits (computed redundantly on all lanes)
    float m  = fmaxf(p0, fmaxf(p1, p2));
    float e0 = expf(p0 - m), e1 = expf(p1 - m), e2 = expf(p2 - m);
    float inv = 1.0f / (e0 + e1 + e2);

    if (j == 0) coef_out[s] = make_float4(e0 * inv, e1 * inv, e2 * inv, 0.0f);
}

// ---------------------------------------------------------------------------
// Kernel B: fused 4-channel GEMM + epilogue combine.
//   acc[c] (c=0..2): x-tile @ Basis_c-tile,  acc[3]: x-tile @ Bias-tile
//   out = coef.x*acc0 + coef.y*acc1 + coef.z*acc2 + acc3
// Tile: BM=64 x BN=32, BK=16, 256 threads (16x16), thread tile 4 rows x 2 cols.
// ---------------------------------------------------------------------------
__global__ __launch_bounds__(256) void gemm_kernel(
    const float*  __restrict__ x,    // [1024, 512]
    const float*  __restrict__ w3,   // [512*512, 3]   element (i*512+o, k)
    const float*  __restrict__ b3,   // [512*512]
    const float4* __restrict__ coef, // [1024]
    float*        __restrict__ out)  // [1024, 512]
{
    // +4 pad -> row stride 68 floats = 272 B (multiple of 16 B for float4 reads)
    __shared__ float xs[BK][BM + 4];   // transposed x tile: xs[kk][m]
    __shared__ float ws[BK][4][BN];    // [kk][basis0..2, bias][o]

    const int t    = threadIdx.x;
    const int tx   = t & 15;   // col group: cols tx*2, tx*2+1
    const int ty   = t >> 4;   // row group: rows ty*4 .. ty*4+3
    const int row0 = blockIdx.y * BM;
    const int o0   = blockIdx.x * BN;

    float acc[4][2][4];  // [row i][col j][channel c]
#pragma unroll
    for (int i = 0; i < 4; ++i)
#pragma unroll
        for (int j = 0; j < 2; ++j)
#pragma unroll
            for (int c = 0; c < 4; ++c) acc[i][j][c] = 0.0f;

    for (int k0 = 0; k0 < IN_DIM; k0 += BK) {
        // ---- stage x tile (transposed): one float4 per thread ----
        {
            const int m   = t >> 2;          // 0..63
            const int kkb = (t & 3) * 4;     // 0,4,8,12
            float4 v = *(const float4*)(x + (long)(row0 + m) * IN_DIM + k0 + kkb);
            xs[kkb + 0][m] = v.x;
            xs[kkb + 1][m] = v.y;
            xs[kkb + 2][m] = v.z;
            xs[kkb + 3][m] = v.w;
        }
        // ---- stage W tile: 512 (kk,o) positions, 2 per thread, 4 ch each ----
#pragma unroll
        for (int r = 0; r < 2; ++r) {
            const int pos = t + r * 256;
            const int kk  = pos >> 5;        // 0..15
            const int o   = pos & 31;        // 0..31
            const long g  = (long)(k0 + kk) * OUT_DIM + (o0 + o);
            const float* wp = w3 + g * 3;
            ws[kk][0][o] = wp[0];
            ws[kk][1][o] = wp[1];
            ws[kk][2][o] = wp[2];
            ws[kk][3][o] = b3[g];
        }
        __syncthreads();

        // ---- compute ----
#pragma unroll
        for (int kk = 0; kk < BK; ++kk) {
            const float4 av = *(const float4*)&xs[kk][ty * 4];
            const float a[4] = {av.x, av.y, av.z, av.w};
#pragma unroll
            for (int c = 0; c < 4; ++c) {
                const float2 wv = *(const float2*)&ws[kk][c][tx * 2];
#pragma unroll
                for (int i = 0; i < 4; ++i) {
                    acc[i][0][c] = fmaf(a[i], wv.x, acc[i][0][c]);
                    acc[i][1][c] = fmaf(a[i], wv.y, acc[i][1][c]);
                }
            }
        }
        __syncthreads();
    }

    // ---- epilogue: combine channels with per-row softmax coefficients ----
#pragma unroll
    for (int i = 0; i < 4; ++i) {
        const int r = row0 + ty * 4 + i;
        const float4 cf = coef[r];
#pragma unroll
        for (int j = 0; j < 2; ++j) {
            float v = acc[i][j][3];
            v = fmaf(acc[i][j][0], cf.x, v);
            v = fmaf(acc[i][j][1], cf.y, v);
            v = fmaf(acc[i][j][2], cf.z, v);
            out[(long)r * OUT_DIM + o0 + tx * 2 + j] = v;
        }
    }
}

// ---------------------------------------------------------------------------
extern "C" void kernel_launch(void* const* d_in, const int* in_sizes, int n_in,
                              void* d_out, int out_size, void* d_ws, size_t ws_size,
                              hipStream_t stream) {
    const float* x     = (const float*)d_in[0];
    const int*   idx_a = (const int*)  d_in[1];
    const int*   idx_c = (const int*)  d_in[2];
    const float* emb_a = (const float*)d_in[3];
    const float* emb_c = (const float*)d_in[4];
    const float* W1    = (const float*)d_in[5];
    const float* b1    = (const float*)d_in[6];
    const float* W2    = (const float*)d_in[7];
    const float* W3    = (const float*)d_in[8];
    const float* b3    = (const float*)d_in[9];
    float*       out   = (float*)d_out;

    float4* coef = (float4*)d_ws;  // [1024] float4, 16 KB scratch

    coef_kernel<<<B_SZ, 64, 0, stream>>>(idx_a, idx_c, emb_a, emb_c, W1, b1, W2, coef);

    dim3 grid(OUT_DIM / BN, B_SZ / BM);  // 16 x 16 = 256 blocks
    gemm_kernel<<<grid, 256, 0, stream>>>(x, W3, b3, coef, out);
}

// Round 4
// 113.238 us; speedup vs baseline: 1.1441x; 1.1441x over previous
//
#include <hip/hip_runtime.h>
#include <math.h>

#define B_SZ    1024
#define IN_DIM  512
#define OUT_DIM 512
#define EMB_DIM 64
#define KQ      64

#define BM 64
#define BN 32
#define BK 16
#define KSPLIT 4
#define KCHUNK (IN_DIM / KSPLIT)   // 128

// ---------------------------------------------------------------------------
// Kernel A: coef[b] = softmax(W2 @ tanh(W1 @ concat(emb_a, emb_c) + b1))
// One wave per sample; lane j owns h[j]. Also zeroes out[] row s (needed by
// the split-K atomicAdd in kernel B; stream order guarantees completion).
// ---------------------------------------------------------------------------
__global__ __launch_bounds__(64) void coef_kernel(
    const int*   __restrict__ idx_a,
    const int*   __restrict__ idx_c,
    const float* __restrict__ emb_a,
    const float* __restrict__ emb_c,
    const float* __restrict__ W1,
    const float* __restrict__ b1,
    const float* __restrict__ W2,
    float4*      __restrict__ coef_out,
    float*       __restrict__ out)      // [B, OUT] -- zeroed here
{
    const int s = blockIdx.x;
    const int j = threadIdx.x;  // 0..63

    // zero this sample's output row: 64 lanes x 8 floats = 512
    float4 z = make_float4(0.f, 0.f, 0.f, 0.f);
    float4* orow = (float4*)(out + (long)s * OUT_DIM);
    orow[j]       = z;
    orow[j + 64]  = z;

    const int ia = idx_a[s];
    const int ic = idx_c[s];

    const float4* ea  = (const float4*)(emb_a + (long)ia * EMB_DIM);
    const float4* ec  = (const float4*)(emb_c + (long)ic * EMB_DIM);
    const float4* w1a = (const float4*)(W1 + (long)j * (2 * EMB_DIM));
    const float4* w1c = (const float4*)(W1 + (long)j * (2 * EMB_DIM) + EMB_DIM);

    float acc = b1[j];
#pragma unroll
    for (int q = 0; q < EMB_DIM / 4; ++q) {
        float4 e = ea[q];
        float4 w = w1a[q];
        acc = fmaf(e.x, w.x, acc);
        acc = fmaf(e.y, w.y, acc);
        acc = fmaf(e.z, w.z, acc);
        acc = fmaf(e.w, w.w, acc);
    }
#pragma unroll
    for (int q = 0; q < EMB_DIM / 4; ++q) {
        float4 e = ec[q];
        float4 w = w1c[q];
        acc = fmaf(e.x, w.x, acc);
        acc = fmaf(e.y, w.y, acc);
        acc = fmaf(e.z, w.z, acc);
        acc = fmaf(e.w, w.w, acc);
    }

    float h = tanhf(acc);

    float p0 = W2[0 * KQ + j] * h;
    float p1 = W2[1 * KQ + j] * h;
    float p2 = W2[2 * KQ + j] * h;
#pragma unroll
    for (int off = 32; off > 0; off >>= 1) {
        p0 += __shfl_xor(p0, off);
        p1 += __shfl_xor(p1, off);
        p2 += __shfl_xor(p2, off);
    }

    float m  = fmaxf(p0, fmaxf(p1, p2));
    float e0 = expf(p0 - m), e1 = expf(p1 - m), e2 = expf(p2 - m);
    float inv = 1.0f / (e0 + e1 + e2);

    if (j == 0) coef_out[s] = make_float4(e0 * inv, e1 * inv, e2 * inv, 0.0f);
}

// ---------------------------------------------------------------------------
// Kernel B: split-K fused 4-channel GEMM + epilogue combine + atomicAdd.
//   blockIdx.z selects a K-chunk of 128. Each block computes the partial
//   acc[c] over its chunk, combines with per-row softmax coefs (bias channel
//   splits correctly across chunks since b3's K-rows are disjoint), atomicAdds.
// Tile: BM=64 x BN=32, BK=16, 256 threads, thread tile 4 rows x 2 cols x 4 ch.
// Grid 16 x 16 x 4 = 1024 blocks -> 4 blocks/CU -> 16 waves/CU (4/SIMD).
// ---------------------------------------------------------------------------
__global__ __launch_bounds__(256, 4) void gemm_kernel(
    const float*  __restrict__ x,    // [1024, 512]
    const float*  __restrict__ w3,   // [512*512, 3]
    const float*  __restrict__ b3,   // [512*512]
    const float4* __restrict__ coef, // [1024]
    float*        __restrict__ out)  // [1024, 512] (pre-zeroed)
{
    __shared__ float xs[BK][BM + 4];   // transposed x tile: xs[kk][m]
    __shared__ float ws[BK][4][BN];    // [kk][basis0..2, bias][o]

    const int t    = threadIdx.x;
    const int tx   = t & 15;
    const int ty   = t >> 4;
    const int row0 = blockIdx.y * BM;
    const int o0   = blockIdx.x * BN;
    const int kb   = blockIdx.z * KCHUNK;

    float acc[4][2][4];
#pragma unroll
    for (int i = 0; i < 4; ++i)
#pragma unroll
        for (int j = 0; j < 2; ++j)
#pragma unroll
            for (int c = 0; c < 4; ++c) acc[i][j][c] = 0.0f;

    for (int k0 = kb; k0 < kb + KCHUNK; k0 += BK) {
        {
            const int m   = t >> 2;
            const int kkb = (t & 3) * 4;
            float4 v = *(const float4*)(x + (long)(row0 + m) * IN_DIM + k0 + kkb);
            xs[kkb + 0][m] = v.x;
            xs[kkb + 1][m] = v.y;
            xs[kkb + 2][m] = v.z;
            xs[kkb + 3][m] = v.w;
        }
#pragma unroll
        for (int r = 0; r < 2; ++r) {
            const int pos = t + r * 256;
            const int kk  = pos >> 5;
            const int o   = pos & 31;
            const long g  = (long)(k0 + kk) * OUT_DIM + (o0 + o);
            const float* wp = w3 + g * 3;
            ws[kk][0][o] = wp[0];
            ws[kk][1][o] = wp[1];
            ws[kk][2][o] = wp[2];
            ws[kk][3][o] = b3[g];
        }
        __syncthreads();

#pragma unroll
        for (int kk = 0; kk < BK; ++kk) {
            const float4 av = *(const float4*)&xs[kk][ty * 4];
            const float a[4] = {av.x, av.y, av.z, av.w};
#pragma unroll
            for (int c = 0; c < 4; ++c) {
                const float2 wv = *(const float2*)&ws[kk][c][tx * 2];
#pragma unroll
                for (int i = 0; i < 4; ++i) {
                    acc[i][0][c] = fmaf(a[i], wv.x, acc[i][0][c]);
                    acc[i][1][c] = fmaf(a[i], wv.y, acc[i][1][c]);
                }
            }
        }
        __syncthreads();
    }

    // epilogue: combine channels with softmax coefs, atomicAdd the partial
#pragma unroll
    for (int i = 0; i < 4; ++i) {
        const int r = row0 + ty * 4 + i;
        const float4 cf = coef[r];
#pragma unroll
        for (int j = 0; j < 2; ++j) {
            float v = acc[i][j][3];
            v = fmaf(acc[i][j][0], cf.x, v);
            v = fmaf(acc[i][j][1], cf.y, v);
            v = fmaf(acc[i][j][2], cf.z, v);
            atomicAdd(&out[(long)r * OUT_DIM + o0 + tx * 2 + j], v);
        }
    }
}

// ---------------------------------------------------------------------------
extern "C" void kernel_launch(void* const* d_in, const int* in_sizes, int n_in,
                              void* d_out, int out_size, void* d_ws, size_t ws_size,
                              hipStream_t stream) {
    const float* x     = (const float*)d_in[0];
    const int*   idx_a = (const int*)  d_in[1];
    const int*   idx_c = (const int*)  d_in[2];
    const float* emb_a = (const float*)d_in[3];
    const float* emb_c = (const float*)d_in[4];
    const float* W1    = (const float*)d_in[5];
    const float* b1    = (const float*)d_in[6];
    const float* W2    = (const float*)d_in[7];
    const float* W3    = (const float*)d_in[8];
    const float* b3    = (const float*)d_in[9];
    float*       out   = (float*)d_out;

    float4* coef = (float4*)d_ws;

    coef_kernel<<<B_SZ, 64, 0, stream>>>(idx_a, idx_c, emb_a, emb_c, W1, b1, W2,
                                         coef, out);

    dim3 grid(OUT_DIM / BN, B_SZ / BM, KSPLIT);  // 16 x 16 x 4 = 1024 blocks
    gemm_kernel<<<grid, 256, 0, stream>>>(x, W3, b3, coef, out);
}